// Round 7
// baseline (281.864 us; speedup 1.0000x reference)
//
#include <hip/hip_runtime.h>
#include <stdint.h>
#include <math.h>

typedef __bf16 bf16_t;
typedef __attribute__((ext_vector_type(8))) __bf16 bf16x8;
typedef __attribute__((ext_vector_type(4))) __bf16 bf16x4;
typedef __attribute__((ext_vector_type(4))) float f32x4;

#define N_TOK 4096
#define D_MODEL 1024
#define HEADS 16
#define DH 64
// p = exp(8*dot - 8.125) = exp2(dot*C1 - C2); constant shift cancels in softmax.
#define C1 11.541560327111707f   // 8 * log2(e)
#define C2 11.721897207207671f   // 8.125 * log2(e)

// async global->LDS 16B copy (dest = wave-uniform base + lane*16)
__device__ __forceinline__ void async_copy16(const void* g, void* l) {
    __builtin_amdgcn_global_load_lds(
        (const __attribute__((address_space(1))) unsigned int*)g,
        (__attribute__((address_space(3))) unsigned int*)l, 16, 0, 0);
}

// ---------------- cast x -> bf16 ----------------
__global__ __launch_bounds__(256) void cast_x_kernel(const float* __restrict__ x,
                                                     bf16_t* __restrict__ xb) {
    int i = (blockIdx.x * 256 + threadIdx.x) * 4;
    float4 v = *(const float4*)(x + i);
    bf16x4 o;
    o[0] = (bf16_t)v.x; o[1] = (bf16_t)v.y; o[2] = (bf16_t)v.z; o[3] = (bf16_t)v.w;
    *(bf16x4*)(xb + i) = o;
}

// ------- transpose + cast W[k][n] -> Wt[n][k] bf16 (q,k,v into one 3072-row buf) ----
__global__ __launch_bounds__(256) void transpose_w_kernel(
    const float* __restrict__ W0, const float* __restrict__ W1,
    const float* __restrict__ W2, const float* __restrict__ W3,
    bf16_t* __restrict__ T0, bf16_t* __restrict__ T1,
    bf16_t* __restrict__ T2, bf16_t* __restrict__ T3) {
    __shared__ bf16_t t[64][72];
    const float* W; bf16_t* T;
    switch (blockIdx.z) {
        case 0: W = W0; T = T0; break;
        case 1: W = W1; T = T1; break;
        case 2: W = W2; T = T2; break;
        default: W = W3; T = T3; break;
    }
    int k0 = blockIdx.x * 64, n0 = blockIdx.y * 64;
    int tx = threadIdx.x & 63, ty = threadIdx.x >> 6;
#pragma unroll
    for (int i = 0; i < 16; i++) {
        int kl = ty * 16 + i;
        t[kl][tx] = (bf16_t)W[(size_t)(k0 + kl) * D_MODEL + n0 + tx];
    }
    __syncthreads();
#pragma unroll
    for (int i = 0; i < 16; i++) {
        int nl = ty * 16 + i;
        T[(size_t)(n0 + nl) * D_MODEL + k0 + tx] = t[tx][nl];
    }
}

// ------- 128x128 MFMA GEMM, swizzled global_load_lds staging, 4 waves x (64x64) -----
// C[M][ldc] tile = A[M][1024] * Bt[N][1024]^T ; optional fused L2-norm per 64-col head
template <int WRITE_F32, int NORM>
__global__ __launch_bounds__(256) void gemm_tile(const bf16_t* __restrict__ A,
                                                 const bf16_t* __restrict__ Bt,
                                                 void* __restrict__ Cout, int ldc) {
    constexpr int K = D_MODEL;
    __shared__ __align__(16) bf16_t As[128 * 32];
    __shared__ __align__(16) bf16_t Bs[128 * 32];
    const int tid = threadIdx.x;
    const int m0 = blockIdx.y * 128;
    const int n0 = blockIdx.x * 128;
    const int wave = tid >> 6;
    const int lane = tid & 63;
    const int l15 = lane & 15;
    const int quad = lane >> 4;
    const int wm = (wave >> 1) * 64;
    const int wn = (wave & 1) * 64;
    const int fsw = quad ^ ((l15 >> 1) & 3);      // read-side swizzled chunk
    f32x4 acc[4][4] = {};

    const int srow = tid >> 2;
    const int cg = (tid & 3) ^ ((srow >> 1) & 3); // global chunk (same for row+64)
    const bf16_t* gA = A + (size_t)(m0 + srow) * K + cg * 8;
    const bf16_t* gB = Bt + (size_t)(n0 + srow) * K + cg * 8;
    bf16_t* lA = &As[tid * 8];
    bf16_t* lB = &Bs[tid * 8];
    constexpr int HGAP = 64 * K;

    for (int kt = 0; kt < K; kt += 32) {
        __syncthreads();
        async_copy16(gA + kt, lA);
        async_copy16(gA + HGAP + kt, lA + 2048);
        async_copy16(gB + kt, lB);
        async_copy16(gB + HGAP + kt, lB + 2048);
        __syncthreads();
        bf16x8 af[4], bfr[4];
#pragma unroll
        for (int mi = 0; mi < 4; mi++)
            af[mi] = *(const bf16x8*)(&As[(wm + mi * 16 + l15) * 32 + fsw * 8]);
#pragma unroll
        for (int ni = 0; ni < 4; ni++)
            bfr[ni] = *(const bf16x8*)(&Bs[(wn + ni * 16 + l15) * 32 + fsw * 8]);
#pragma unroll
        for (int mi = 0; mi < 4; mi++)
#pragma unroll
            for (int ni = 0; ni < 4; ni++)
                acc[mi][ni] = __builtin_amdgcn_mfma_f32_16x16x32_bf16(
                    af[mi], bfr[ni], acc[mi][ni], 0, 0, 0);
    }

    if (NORM && n0 < 2048) {   // wave's 64-col span == one head: fused F.normalize
#pragma unroll
        for (int mi = 0; mi < 4; mi++)
#pragma unroll
            for (int r = 0; r < 4; r++) {
                float s = 0.f;
#pragma unroll
                for (int ni = 0; ni < 4; ni++) {
                    float v = acc[mi][ni][r];
                    s += v * v;
                }
                s += __shfl_xor(s, 1);
                s += __shfl_xor(s, 2);
                s += __shfl_xor(s, 4);
                s += __shfl_xor(s, 8);
                float sc = 1.0f / fmaxf(sqrtf(s), 1e-12f);
#pragma unroll
                for (int ni = 0; ni < 4; ni++) acc[mi][ni][r] *= sc;
            }
    }
#pragma unroll
    for (int mi = 0; mi < 4; mi++)
#pragma unroll
        for (int ni = 0; ni < 4; ni++)
#pragma unroll
            for (int r = 0; r < 4; r++) {
                int row = m0 + wm + mi * 16 + quad * 4 + r;
                int col = n0 + wn + ni * 16 + l15;
                float v = acc[mi][ni][r];
                if (WRITE_F32)
                    ((float*)Cout)[(size_t)row * ldc + col] = v;
                else
                    ((bf16_t*)Cout)[(size_t)row * ldc + col] = (bf16_t)v;
            }
}

// ---------------- V (QKV cols 2048..3071) -> Vt[h][d][n] ----------------
__global__ __launch_bounds__(256) void transpose_v_kernel(const bf16_t* __restrict__ QKV,
                                                          bf16_t* __restrict__ Vt) {
    __shared__ bf16_t t[64][72];
    int n0 = blockIdx.x * 64;
    int h = blockIdx.y;
    int tx = threadIdx.x & 63, ty = threadIdx.x >> 6;
#pragma unroll
    for (int i = 0; i < 16; i++) {
        int nl = ty * 16 + i;
        t[nl][tx] = QKV[(size_t)(n0 + nl) * 3072 + 2048 + h * DH + tx];
    }
    __syncthreads();
#pragma unroll
    for (int i = 0; i < 16; i++) {
        int dl = ty * 16 + i;
        Vt[(size_t)(h * DH + dl) * N_TOK + n0 + tx] = t[tx][dl];
    }
}

// ---------------- flash attention: shared LDS-staged K/V, 128 q-rows/block ----------
// block = 4 waves x 32 contiguous q-rows of one head, all marching the same j-tiles.
// K/V staged once per block via swizzled global_load_lds (dbuf, 1 barrier/tile):
// 4x fewer L1 line touches than per-wave global fragment reads. Direct O write.
__global__ __launch_bounds__(256) void attn_kernel(const bf16_t* __restrict__ QKV,
                                                   const bf16_t* __restrict__ Vt,
                                                   bf16_t* __restrict__ O) {
    __shared__ __align__(16) bf16_t Ks[2][2048];   // [buf][32 j x 64 d] swizzled
    __shared__ __align__(16) bf16_t Vs[2][2048];   // [buf][64 d x 32 j] swizzled
    __shared__ __align__(16) bf16_t Pt[4][32 * 40];
    const int tid = threadIdx.x;
    const int wave = tid >> 6;
    const int lane = tid & 63;
    const int l15 = lane & 15;
    const int quad = lane >> 4;
    const int fsw = quad ^ ((l15 >> 1) & 3);

    const int xcd = blockIdx.x & 7;
    const int t = blockIdx.x >> 3;          // 0..63
    const int h = xcd * 2 + (t & 1);        // 2 heads per XCD for K/V L2 residency
    const int g = 31 - (t >> 1);            // 128-row i-group, heaviest first
    const int i0 = g * 128 + wave * 32;     // this wave's 32-row strip
    const int jt_blk = g * 4 + 3;           // block's last j-tile (wave 3's diagonal)
    const int jtw = g * 4 + wave;           // this wave's diagonal tile

    const bf16_t* Qb = QKV + h * DH;
    const bf16_t* Kb = QKV + 1024 + h * DH;
    const bf16_t* Vb = Vt + (size_t)h * DH * N_TOK;
    bf16_t* P = Pt[wave];

    bf16x8 aq[2][2];
#pragma unroll
    for (int s_ = 0; s_ < 2; s_++)
#pragma unroll
        for (int kd = 0; kd < 2; kd++)
            aq[s_][kd] = *(const bf16x8*)(Qb + (size_t)(i0 + s_ * 16 + l15) * 3072 +
                                          kd * 32 + quad * 8);

    f32x4 acc[2][4] = {};
    float l_part[2][4] = {};

    // staging: K chunk (row=tid>>3, c=(tid&7)^(row&7)); V chunk (d=tid>>2, c=(tid&3)^((d>>1)&3))
    const int krow = tid >> 3;
    const int kc = (tid & 7) ^ (krow & 7);
    const bf16_t* gK = Kb + (size_t)krow * 3072 + kc * 8;
    const int vd = tid >> 2;
    const int vc = (tid & 3) ^ ((vd >> 1) & 3);
    const bf16_t* gV = Vb + (size_t)vd * N_TOK + vc * 8;

    // preload tile 0 into buf 0
    async_copy16(gK, &Ks[0][tid * 8]);
    async_copy16(gV, &Vs[0][tid * 8]);

    for (int jt = 0; jt <= jt_blk; jt++) {
        __syncthreads();                    // drains vmcnt: buf[jt&1] ready; prior reads done
        if (jt < jt_blk) {                  // prefetch next tile into other buf
            const int b = (jt + 1) & 1;
            async_copy16(gK + (size_t)(jt + 1) * 32 * 3072, &Ks[b][tid * 8]);
            async_copy16(gV + (jt + 1) * 32, &Vs[b][tid * 8]);
        }
        if (jt > jtw) continue;             // wave-uniform; still hits barriers
        const bf16_t* KS = Ks[jt & 1];
        const bf16_t* VS = Vs[jt & 1];

        // ---- QK^T ----
        bf16x8 bk[2][2];
#pragma unroll
        for (int kd = 0; kd < 2; kd++)
#pragma unroll
            for (int jh = 0; jh < 2; jh++)
                bk[kd][jh] = *(const bf16x8*)(&KS[(jh * 16 + l15) * 64 +
                                                  (((kd * 4 + quad) ^ (l15 & 7)) * 8)]);
        f32x4 sS[2][2] = {};
#pragma unroll
        for (int kd = 0; kd < 2; kd++)
#pragma unroll
            for (int s_ = 0; s_ < 2; s_++) {
                sS[s_][0] = __builtin_amdgcn_mfma_f32_16x16x32_bf16(aq[s_][kd], bk[kd][0], sS[s_][0], 0, 0, 0);
                sS[s_][1] = __builtin_amdgcn_mfma_f32_16x16x32_bf16(aq[s_][kd], bk[kd][1], sS[s_][1], 0, 0, 0);
            }
        // ---- softmax (fixed max) + P store ----
        if (jt == jtw) {                    // diagonal tile: causal mask (i0 == j0)
#pragma unroll
            for (int s_ = 0; s_ < 2; s_++)
#pragma unroll
                for (int r = 0; r < 4; r++) {
                    const int il = s_ * 16 + quad * 4 + r;
                    float p0 = (l15 > il) ? 0.f : __builtin_amdgcn_exp2f(sS[s_][0][r] * C1 - C2);
                    float p1 = (16 + l15 > il) ? 0.f : __builtin_amdgcn_exp2f(sS[s_][1][r] * C1 - C2);
                    l_part[s_][r] += p0 + p1;
                    P[il * 40 + l15] = (bf16_t)p0;
                    P[il * 40 + 16 + l15] = (bf16_t)p1;
                }
        } else {
#pragma unroll
            for (int s_ = 0; s_ < 2; s_++)
#pragma unroll
                for (int r = 0; r < 4; r++) {
                    const int il = s_ * 16 + quad * 4 + r;
                    float p0 = __builtin_amdgcn_exp2f(sS[s_][0][r] * C1 - C2);
                    float p1 = __builtin_amdgcn_exp2f(sS[s_][1][r] * C1 - C2);
                    l_part[s_][r] += p0 + p1;
                    P[il * 40 + l15] = (bf16_t)p0;
                    P[il * 40 + 16 + l15] = (bf16_t)p1;
                }
        }
        // ---- P (C-layout) -> A-layout via wave-private LDS; PV ----
        bf16x8 bv[4];
#pragma unroll
        for (int ni = 0; ni < 4; ni++)
            bv[ni] = *(const bf16x8*)(&VS[(ni * 16 + l15) * 32 + fsw * 8]);
#pragma unroll
        for (int s_ = 0; s_ < 2; s_++) {
            bf16x8 ap = *(const bf16x8*)(&P[(s_ * 16 + l15) * 40 + quad * 8]);
#pragma unroll
            for (int ni = 0; ni < 4; ni++)
                acc[s_][ni] = __builtin_amdgcn_mfma_f32_16x16x32_bf16(ap, bv[ni], acc[s_][ni], 0, 0, 0);
        }
    }

    float inv[2][4];
#pragma unroll
    for (int s_ = 0; s_ < 2; s_++)
#pragma unroll
        for (int r = 0; r < 4; r++) {
            float l = l_part[s_][r];
            l += __shfl_xor(l, 1);
            l += __shfl_xor(l, 2);
            l += __shfl_xor(l, 4);
            l += __shfl_xor(l, 8);
            inv[s_][r] = 1.0f / l;
        }
#pragma unroll
    for (int s_ = 0; s_ < 2; s_++)
#pragma unroll
        for (int ni = 0; ni < 4; ni++)
#pragma unroll
            for (int r = 0; r < 4; r++) {
                int i = i0 + s_ * 16 + quad * 4 + r;
                int col = h * DH + ni * 16 + l15;
                O[(size_t)i * D_MODEL + col] = (bf16_t)(acc[s_][ni][r] * inv[s_][r]);
            }
}

extern "C" void kernel_launch(void* const* d_in, const int* in_sizes, int n_in,
                              void* d_out, int out_size, void* d_ws, size_t ws_size,
                              hipStream_t stream) {
    const float* x  = (const float*)d_in[0];
    const float* Wq = (const float*)d_in[1];
    const float* Wk = (const float*)d_in[2];
    const float* Wv = (const float*)d_in[3];
    const float* Wo = (const float*)d_in[4];
    float* out = (float*)d_out;
    char* ws = (char*)d_ws;
    const size_t MB = 1024 * 1024;
    bf16_t* xb   = (bf16_t*)(ws);             // 8 MB
    bf16_t* Wt3  = (bf16_t*)(ws + 8 * MB);    // 6 MB  [3072][1024] q|k|v
    bf16_t* Wot  = (bf16_t*)(ws + 14 * MB);   // 2 MB
    bf16_t* QKV  = (bf16_t*)(ws + 16 * MB);   // 24 MB [4096][3072]
    bf16_t* Vt   = (bf16_t*)(ws + 40 * MB);   // 8 MB  [16][64][4096]
    bf16_t* Ob   = (bf16_t*)(ws + 48 * MB);   // 8 MB  -> ends at 56 MB

    cast_x_kernel<<<4096, 256, 0, stream>>>(x, xb);
    dim3 gw(16, 16, 4);
    transpose_w_kernel<<<gw, 256, 0, stream>>>(Wq, Wk, Wv, Wo,
                                               Wt3, Wt3 + 1024 * 1024, Wt3 + 2 * 1024 * 1024, Wot);
    dim3 gqkv(3072 / 128, N_TOK / 128);
    gemm_tile<0, 1><<<gqkv, 256, 0, stream>>>(xb, Wt3, QKV, 3072);
    dim3 gv(N_TOK / 64, HEADS);
    transpose_v_kernel<<<gv, 256, 0, stream>>>(QKV, Vt);
    attn_kernel<<<512, 256, 0, stream>>>(QKV, Vt, Ob);
    dim3 go(D_MODEL / 128, N_TOK / 128);
    gemm_tile<1, 0><<<go, 256, 0, stream>>>(Ob, Wot, out, D_MODEL);
}

// Round 8
// 251.956 us; speedup vs baseline: 1.1187x; 1.1187x over previous
//
#include <hip/hip_runtime.h>
#include <stdint.h>
#include <math.h>

typedef __bf16 bf16_t;
typedef __attribute__((ext_vector_type(8))) __bf16 bf16x8;
typedef __attribute__((ext_vector_type(4))) __bf16 bf16x4;
typedef __attribute__((ext_vector_type(4))) float f32x4;

#define N_TOK 4096
#define D_MODEL 1024
#define HEADS 16
#define DH 64
// p = exp(8*dot - 8.125) = exp2(dot*C1 - C2); constant shift cancels in softmax.
#define C1 11.541560327111707f   // 8 * log2(e)
#define C2 11.721897207207671f   // 8.125 * log2(e)

// async global->LDS 16B copy (dest = wave-uniform base + lane*16)
__device__ __forceinline__ void async_copy16(const void* g, void* l) {
    __builtin_amdgcn_global_load_lds(
        (const __attribute__((address_space(1))) unsigned int*)g,
        (__attribute__((address_space(3))) unsigned int*)l, 16, 0, 0);
}

// ---------------- cast x -> bf16 ----------------
__global__ __launch_bounds__(256) void cast_x_kernel(const float* __restrict__ x,
                                                     bf16_t* __restrict__ xb) {
    int i = (blockIdx.x * 256 + threadIdx.x) * 4;
    float4 v = *(const float4*)(x + i);
    bf16x4 o;
    o[0] = (bf16_t)v.x; o[1] = (bf16_t)v.y; o[2] = (bf16_t)v.z; o[3] = (bf16_t)v.w;
    *(bf16x4*)(xb + i) = o;
}

// ------- transpose + cast W[k][n] -> Wt[n][k] bf16 (q,k,v into one 3072-row buf) ----
__global__ __launch_bounds__(256) void transpose_w_kernel(
    const float* __restrict__ W0, const float* __restrict__ W1,
    const float* __restrict__ W2, const float* __restrict__ W3,
    bf16_t* __restrict__ T0, bf16_t* __restrict__ T1,
    bf16_t* __restrict__ T2, bf16_t* __restrict__ T3) {
    __shared__ bf16_t t[64][72];
    const float* W; bf16_t* T;
    switch (blockIdx.z) {
        case 0: W = W0; T = T0; break;
        case 1: W = W1; T = T1; break;
        case 2: W = W2; T = T2; break;
        default: W = W3; T = T3; break;
    }
    int k0 = blockIdx.x * 64, n0 = blockIdx.y * 64;
    int tx = threadIdx.x & 63, ty = threadIdx.x >> 6;
#pragma unroll
    for (int i = 0; i < 16; i++) {
        int kl = ty * 16 + i;
        t[kl][tx] = (bf16_t)W[(size_t)(k0 + kl) * D_MODEL + n0 + tx];
    }
    __syncthreads();
#pragma unroll
    for (int i = 0; i < 16; i++) {
        int nl = ty * 16 + i;
        T[(size_t)(n0 + nl) * D_MODEL + k0 + tx] = t[tx][nl];
    }
}

// ------- 128x128 MFMA GEMM, BK=64, swizzled global_load_lds staging ----------------
// C[M][ldc] tile = A[M][1024] * Bt[N][1024]^T ; optional fused L2-norm per 64-col head
template <int WRITE_F32, int NORM>
__global__ __launch_bounds__(256) void gemm_tile(const bf16_t* __restrict__ A,
                                                 const bf16_t* __restrict__ Bt,
                                                 void* __restrict__ Cout, int ldc) {
    constexpr int K = D_MODEL;
    __shared__ __align__(16) bf16_t As[128 * 64];   // rows of 64; 16B chunk c at row r = src chunk c^(r&7)
    __shared__ __align__(16) bf16_t Bs[128 * 64];
    const int tid = threadIdx.x;
    const int m0 = blockIdx.y * 128;
    const int n0 = blockIdx.x * 128;
    const int wave = tid >> 6;
    const int lane = tid & 63;
    const int l15 = lane & 15;
    const int quad = lane >> 4;
    const int wm = (wave >> 1) * 64;
    const int wn = (wave & 1) * 64;
    f32x4 acc[4][4] = {};

    // staging: copy i handles chunk idx = tid + 256*i -> row = (tid>>3)+32*i, chunk c = tid&7
    const int srow = tid >> 3;
    const int cs = (tid & 7) ^ (srow & 7);          // source chunk (row&7 invariant across i)
    const bf16_t* gA = A + (size_t)(m0 + srow) * K + cs * 8;
    const bf16_t* gB = Bt + (size_t)(n0 + srow) * K + cs * 8;
    bf16_t* lA = &As[tid * 8];
    bf16_t* lB = &Bs[tid * 8];

    for (int kt = 0; kt < K; kt += 64) {
        __syncthreads();
#pragma unroll
        for (int i = 0; i < 4; i++) {
            async_copy16(gA + (size_t)32 * i * K + kt, lA + 2048 * i);
            async_copy16(gB + (size_t)32 * i * K + kt, lB + 2048 * i);
        }
        __syncthreads();
#pragma unroll
        for (int kd = 0; kd < 2; kd++) {
            bf16x8 af[4], bfr[4];
#pragma unroll
            for (int mi = 0; mi < 4; mi++) {
                int row = wm + mi * 16 + l15;
                af[mi] = *(const bf16x8*)(&As[row * 64 + (((kd * 4 + quad) ^ (l15 & 7)) * 8)]);
            }
#pragma unroll
            for (int ni = 0; ni < 4; ni++) {
                int row = wn + ni * 16 + l15;
                bfr[ni] = *(const bf16x8*)(&Bs[row * 64 + (((kd * 4 + quad) ^ (l15 & 7)) * 8)]);
            }
#pragma unroll
            for (int mi = 0; mi < 4; mi++)
#pragma unroll
                for (int ni = 0; ni < 4; ni++)
                    acc[mi][ni] = __builtin_amdgcn_mfma_f32_16x16x32_bf16(
                        af[mi], bfr[ni], acc[mi][ni], 0, 0, 0);
        }
    }

    if (NORM && n0 < 2048) {   // wave's 64-col span == one head: fused F.normalize
#pragma unroll
        for (int mi = 0; mi < 4; mi++)
#pragma unroll
            for (int r = 0; r < 4; r++) {
                float s = 0.f;
#pragma unroll
                for (int ni = 0; ni < 4; ni++) {
                    float v = acc[mi][ni][r];
                    s += v * v;
                }
                s += __shfl_xor(s, 1);
                s += __shfl_xor(s, 2);
                s += __shfl_xor(s, 4);
                s += __shfl_xor(s, 8);
                float sc = 1.0f / fmaxf(sqrtf(s), 1e-12f);
#pragma unroll
                for (int ni = 0; ni < 4; ni++) acc[mi][ni][r] *= sc;
            }
    }
#pragma unroll
    for (int mi = 0; mi < 4; mi++)
#pragma unroll
        for (int ni = 0; ni < 4; ni++)
#pragma unroll
            for (int r = 0; r < 4; r++) {
                int row = m0 + wm + mi * 16 + quad * 4 + r;
                int col = n0 + wn + ni * 16 + l15;
                float v = acc[mi][ni][r];
                if (WRITE_F32)
                    ((float*)Cout)[(size_t)row * ldc + col] = v;
                else
                    ((bf16_t*)Cout)[(size_t)row * ldc + col] = (bf16_t)v;
            }
}

// ---------------- V (QKV cols 2048..3071) -> Vt[h][d][n] ----------------
__global__ __launch_bounds__(256) void transpose_v_kernel(const bf16_t* __restrict__ QKV,
                                                          bf16_t* __restrict__ Vt) {
    __shared__ bf16_t t[64][72];
    int n0 = blockIdx.x * 64;
    int h = blockIdx.y;
    int tx = threadIdx.x & 63, ty = threadIdx.x >> 6;
#pragma unroll
    for (int i = 0; i < 16; i++) {
        int nl = ty * 16 + i;
        t[nl][tx] = QKV[(size_t)(n0 + nl) * 3072 + 2048 + h * DH + tx];
    }
    __syncthreads();
#pragma unroll
    for (int i = 0; i < 16; i++) {
        int dl = ty * 16 + i;
        Vt[(size_t)(h * DH + dl) * N_TOK + n0 + tx] = t[tx][dl];
    }
}

// ---------------- flash attention v8: S^T trick, no P LDS round-trip ----------------
// S^T = K.Q^T -> C-layout IS a B-fragment under k-enum j(q,jj)=16*(jj>>2)+4q+(jj&3);
// O^T += V^T.P^T straight from registers. Block = 4 waves x 16 q-rows (64-row group),
// K/V tiles staged once per block (swizzled, dbuf, 1 barrier/tile). 1024 blocks.
__global__ __launch_bounds__(256) void attn_kernel(const bf16_t* __restrict__ QKV,
                                                   const bf16_t* __restrict__ Vt,
                                                   bf16_t* __restrict__ O) {
    __shared__ __align__(16) bf16_t Ks[2][2048];   // [buf][32 j x 64 d] chunk c@row r = src c^(r&7)
    __shared__ __align__(16) bf16_t Vs[2][2048];   // [buf][64 d x 32 j] 16B chunk c@row d = src c^((d>>1)&3)
    const int tid = threadIdx.x;
    const int wave = tid >> 6;
    const int lane = tid & 63;
    const int l15 = lane & 15;
    const int quad = lane >> 4;

    const int xcd = blockIdx.x & 7;
    const int t = blockIdx.x >> 3;          // 0..127
    const int h = xcd * 2 + (t & 1);        // 2 heads per XCD
    const int g = 63 - (t >> 1);            // 64-row i-group, heaviest first
    const int i0 = g * 64 + wave * 16;      // this wave's 16 rows
    const int jt_blk = 2 * g + 1;           // block's last j-tile
    const int jtw = 2 * g + (wave >> 1);    // this wave's diagonal tile

    const bf16_t* Qb = QKV + h * DH;
    const bf16_t* Kb = QKV + 1024 + h * DH;
    const bf16_t* Vb = Vt + (size_t)h * DH * N_TOK;

    // Q^T B-fragment: B[k=d][n=i]: lane n=l15 -> row i0+l15, k=quad*8.. contiguous
    bf16x8 aq[2];
#pragma unroll
    for (int kd = 0; kd < 2; kd++)
        aq[kd] = *(const bf16x8*)(Qb + (size_t)(i0 + l15) * 3072 + kd * 32 + quad * 8);

    f32x4 od[4] = {};          // O^T[d=mt*16+quad*4+r][i=l15]
    float l_acc = 0.f;

    // staging: K chunk idx tid -> (row=tid>>3, c=tid&7), src chunk c^(row&7)
    const int krow = tid >> 3;
    const int kc = (tid & 7) ^ (krow & 7);
    const bf16_t* gK = Kb + (size_t)krow * 3072 + kc * 8;
    // V chunk idx tid -> (d=tid>>2, c16=tid&3), src chunk c16^((d>>1)&3)
    const int vd = tid >> 2;
    const int vc = (tid & 3) ^ ((vd >> 1) & 3);
    const bf16_t* gV = Vb + (size_t)vd * N_TOK + vc * 8;

    // preload tile 0 into buf 0
    async_copy16(gK, &Ks[0][tid * 8]);
    async_copy16(gV, &Vs[0][tid * 8]);

    const int ksw = l15 & 7;             // K-tile read swizzle
    const int vsw = (l15 >> 1) & 3;      // V-tile read swizzle (16B chunks)

    for (int jt = 0; jt <= jt_blk; jt++) {
        __syncthreads();                 // drains vmcnt: buf[jt&1] ready; prior reads done
        if (jt < jt_blk) {               // prefetch next tile into other buf
            const int b = (jt + 1) & 1;
            async_copy16(gK + (size_t)(jt + 1) * 32 * 3072, &Ks[b][tid * 8]);
            async_copy16(gV + (jt + 1) * 32, &Vs[b][tid * 8]);
        }
        if (jt > jtw) continue;          // wave-uniform; still hits barriers
        const bf16_t* KS = Ks[jt & 1];
        const bf16_t* VS = Vs[jt & 1];

        // ---- S^T = K.Q^T : A = K-frag (m=j), B = aq (n=i) ----
        bf16x8 ak[2][2];                 // [jh][kd]
#pragma unroll
        for (int jh = 0; jh < 2; jh++)
#pragma unroll
            for (int kd = 0; kd < 2; kd++)
                ak[jh][kd] = *(const bf16x8*)(&KS[(jh * 16 + l15) * 64 +
                                                  (((kd * 4 + quad) ^ ksw) * 8)]);
        f32x4 sj[2] = {};
#pragma unroll
        for (int kd = 0; kd < 2; kd++)
#pragma unroll
            for (int jh = 0; jh < 2; jh++)
                sj[jh] = __builtin_amdgcn_mfma_f32_16x16x32_bf16(ak[jh][kd], aq[kd], sj[jh], 0, 0, 0);

        // ---- softmax (fixed max), pack P^T B-fragment pk8[jj]=p[jj>>2][jj&3] ----
        bf16x8 pk8;
        const int j_base = jt * 32 + quad * 4;
        const int i_row = i0 + l15;
        if (jt == jtw) {                 // diagonal tile: causal mask j > i
#pragma unroll
            for (int r = 0; r < 4; r++) {
                float p0 = (j_base + r > i_row) ? 0.f
                           : __builtin_amdgcn_exp2f(sj[0][r] * C1 - C2);
                float p1 = (j_base + 16 + r > i_row) ? 0.f
                           : __builtin_amdgcn_exp2f(sj[1][r] * C1 - C2);
                l_acc += p0 + p1;
                pk8[r] = (bf16_t)p0;
                pk8[4 + r] = (bf16_t)p1;
            }
        } else {
#pragma unroll
            for (int r = 0; r < 4; r++) {
                float p0 = __builtin_amdgcn_exp2f(sj[0][r] * C1 - C2);
                float p1 = __builtin_amdgcn_exp2f(sj[1][r] * C1 - C2);
                l_acc += p0 + p1;
                pk8[r] = (bf16_t)p0;
                pk8[4 + r] = (bf16_t)p1;
            }
        }

        // ---- O^T += V^T.P^T : A = V-frag (m=d, k-enum j(q,jj)), B = pk8 ----
#pragma unroll
        for (int mt = 0; mt < 4; mt++) {
            const int drow = mt * 16 + l15;
            bf16x4 v0 = *(const bf16x4*)(&VS[drow * 32 + (((quad >> 1) ^ vsw) * 8) + (quad & 1) * 4]);
            bf16x4 v1 = *(const bf16x4*)(&VS[drow * 32 + (((2 + (quad >> 1)) ^ vsw) * 8) + (quad & 1) * 4]);
            bf16x8 vf;
#pragma unroll
            for (int e = 0; e < 4; e++) { vf[e] = v0[e]; vf[4 + e] = v1[e]; }
            od[mt] = __builtin_amdgcn_mfma_f32_16x16x32_bf16(vf, pk8, od[mt], 0, 0, 0);
        }
    }

    // ---- normalize: row sum l for i=l15 lives split across quads ----
    float l = l_acc;
    l += __shfl_xor(l, 16);
    l += __shfl_xor(l, 32);
    float inv = 1.0f / l;

#pragma unroll
    for (int mt = 0; mt < 4; mt++) {
        bf16x4 o;
#pragma unroll
        for (int r = 0; r < 4; r++) o[r] = (bf16_t)(od[mt][r] * inv);
        *(bf16x4*)(&O[(size_t)(i0 + l15) * D_MODEL + h * DH + mt * 16 + quad * 4]) = o;
    }
}

extern "C" void kernel_launch(void* const* d_in, const int* in_sizes, int n_in,
                              void* d_out, int out_size, void* d_ws, size_t ws_size,
                              hipStream_t stream) {
    const float* x  = (const float*)d_in[0];
    const float* Wq = (const float*)d_in[1];
    const float* Wk = (const float*)d_in[2];
    const float* Wv = (const float*)d_in[3];
    const float* Wo = (const float*)d_in[4];
    float* out = (float*)d_out;
    char* ws = (char*)d_ws;
    const size_t MB = 1024 * 1024;
    bf16_t* xb   = (bf16_t*)(ws);             // 8 MB
    bf16_t* Wt3  = (bf16_t*)(ws + 8 * MB);    // 6 MB  [3072][1024] q|k|v
    bf16_t* Wot  = (bf16_t*)(ws + 14 * MB);   // 2 MB
    bf16_t* QKV  = (bf16_t*)(ws + 16 * MB);   // 24 MB [4096][3072]
    bf16_t* Vt   = (bf16_t*)(ws + 40 * MB);   // 8 MB  [16][64][4096]
    bf16_t* Ob   = (bf16_t*)(ws + 48 * MB);   // 8 MB  -> ends at 56 MB

    cast_x_kernel<<<4096, 256, 0, stream>>>(x, xb);
    dim3 gw(16, 16, 4);
    transpose_w_kernel<<<gw, 256, 0, stream>>>(Wq, Wk, Wv, Wo,
                                               Wt3, Wt3 + 1024 * 1024, Wt3 + 2 * 1024 * 1024, Wot);
    dim3 gqkv(3072 / 128, N_TOK / 128);
    gemm_tile<0, 1><<<gqkv, 256, 0, stream>>>(xb, Wt3, QKV, 3072);
    dim3 gv(N_TOK / 64, HEADS);
    transpose_v_kernel<<<gv, 256, 0, stream>>>(QKV, Vt);
    attn_kernel<<<1024, 256, 0, stream>>>(QKV, Vt, Ob);
    dim3 go(D_MODEL / 128, N_TOK / 128);
    gemm_tile<1, 0><<<go, 256, 0, stream>>>(Ob, Wot, out, D_MODEL);
}

// Round 9
// 248.259 us; speedup vs baseline: 1.1354x; 1.0149x over previous
//
#include <hip/hip_runtime.h>
#include <stdint.h>
#include <math.h>

typedef __bf16 bf16_t;
typedef __attribute__((ext_vector_type(8))) __bf16 bf16x8;
typedef __attribute__((ext_vector_type(4))) __bf16 bf16x4;
typedef __attribute__((ext_vector_type(4))) float f32x4;

#define N_TOK 4096
#define D_MODEL 1024
#define HEADS 16
#define DH 64
// p = exp(8*dot - 8.125) = exp2(dot*C1 - C2); constant shift cancels in softmax.
#define C1 11.541560327111707f   // 8 * log2(e)
#define C2 11.721897207207671f   // 8.125 * log2(e)

// async global->LDS 16B copy (dest = wave-uniform base + lane*16)
__device__ __forceinline__ void async_copy16(const void* g, void* l) {
    __builtin_amdgcn_global_load_lds(
        (const __attribute__((address_space(1))) unsigned int*)g,
        (__attribute__((address_space(3))) unsigned int*)l, 16, 0, 0);
}

// ---------------- cast x -> bf16 ----------------
__global__ __launch_bounds__(256) void cast_x_kernel(const float* __restrict__ x,
                                                     bf16_t* __restrict__ xb) {
    int i = (blockIdx.x * 256 + threadIdx.x) * 4;
    float4 v = *(const float4*)(x + i);
    bf16x4 o;
    o[0] = (bf16_t)v.x; o[1] = (bf16_t)v.y; o[2] = (bf16_t)v.z; o[3] = (bf16_t)v.w;
    *(bf16x4*)(xb + i) = o;
}

// ------- transpose + cast W[k][n] -> Wt[n][k] bf16 (q,k,v into one 3072-row buf) ----
__global__ __launch_bounds__(256) void transpose_w_kernel(
    const float* __restrict__ W0, const float* __restrict__ W1,
    const float* __restrict__ W2, const float* __restrict__ W3,
    bf16_t* __restrict__ T0, bf16_t* __restrict__ T1,
    bf16_t* __restrict__ T2, bf16_t* __restrict__ T3) {
    __shared__ bf16_t t[64][72];
    const float* W; bf16_t* T;
    switch (blockIdx.z) {
        case 0: W = W0; T = T0; break;
        case 1: W = W1; T = T1; break;
        case 2: W = W2; T = T2; break;
        default: W = W3; T = T3; break;
    }
    int k0 = blockIdx.x * 64, n0 = blockIdx.y * 64;
    int tx = threadIdx.x & 63, ty = threadIdx.x >> 6;
#pragma unroll
    for (int i = 0; i < 16; i++) {
        int kl = ty * 16 + i;
        t[kl][tx] = (bf16_t)W[(size_t)(k0 + kl) * D_MODEL + n0 + tx];
    }
    __syncthreads();
#pragma unroll
    for (int i = 0; i < 16; i++) {
        int nl = ty * 16 + i;
        T[(size_t)(n0 + nl) * D_MODEL + k0 + tx] = t[tx][nl];
    }
}

// ------- 128x128 MFMA GEMM, m97-exact staging (sequential chunks, BK=32) -----------
// C[M][ldc] tile = A[M][1024] * Bt[N][1024]^T ; optional fused L2-norm per 64-col head
// Read-side bank conflicts accepted (m97: 1.7e7 conflicts yet 874 TF — cheap at
// GEMM's 16-MFMA-per-8-ds_read density). Staging is perfectly lane-sequential.
template <int WRITE_F32, int NORM>
__global__ __launch_bounds__(256) void gemm_tile(const bf16_t* __restrict__ A,
                                                 const bf16_t* __restrict__ Bt,
                                                 void* __restrict__ Cout, int ldc) {
    constexpr int K = D_MODEL;
    __shared__ __align__(16) bf16_t As[128 * 32];
    __shared__ __align__(16) bf16_t Bs[128 * 32];
    const int tid = threadIdx.x;
    const int m0 = blockIdx.y * 128;
    const int n0 = blockIdx.x * 128;
    const int wave = tid >> 6;
    const int lane = tid & 63;
    const int l15 = lane & 15;
    const int quad = lane >> 4;
    const int wm = (wave >> 1) * 64;
    const int wn = (wave & 1) * 64;
    f32x4 acc[4][4] = {};

    // staging: thread t handles chunks t and t+256; chunk c: row=c>>2, off=(c&3)*8
    const int srow = tid >> 2;
    const int soff = (tid & 3) * 8;
    const bf16_t* gA = A + (size_t)(m0 + srow) * K + soff;
    const bf16_t* gB = Bt + (size_t)(n0 + srow) * K + soff;
    bf16_t* lA = &As[tid * 8];
    bf16_t* lB = &Bs[tid * 8];
    constexpr int HGAP = 64 * K;

    for (int kt = 0; kt < K; kt += 32) {
        __syncthreads();
        async_copy16(gA + kt, lA);
        async_copy16(gA + HGAP + kt, lA + 2048);
        async_copy16(gB + kt, lB);
        async_copy16(gB + HGAP + kt, lB + 2048);
        __syncthreads();
        bf16x8 af[4], bfr[4];
#pragma unroll
        for (int mi = 0; mi < 4; mi++)
            af[mi] = *(const bf16x8*)(&As[(wm + mi * 16 + l15) * 32 + quad * 8]);
#pragma unroll
        for (int ni = 0; ni < 4; ni++)
            bfr[ni] = *(const bf16x8*)(&Bs[(wn + ni * 16 + l15) * 32 + quad * 8]);
#pragma unroll
        for (int mi = 0; mi < 4; mi++)
#pragma unroll
            for (int ni = 0; ni < 4; ni++)
                acc[mi][ni] = __builtin_amdgcn_mfma_f32_16x16x32_bf16(
                    af[mi], bfr[ni], acc[mi][ni], 0, 0, 0);
    }

    if (NORM && n0 < 2048) {   // wave's 64-col span == one head: fused F.normalize
#pragma unroll
        for (int mi = 0; mi < 4; mi++)
#pragma unroll
            for (int r = 0; r < 4; r++) {
                float s = 0.f;
#pragma unroll
                for (int ni = 0; ni < 4; ni++) {
                    float v = acc[mi][ni][r];
                    s += v * v;
                }
                s += __shfl_xor(s, 1);
                s += __shfl_xor(s, 2);
                s += __shfl_xor(s, 4);
                s += __shfl_xor(s, 8);
                float sc = 1.0f / fmaxf(sqrtf(s), 1e-12f);
#pragma unroll
                for (int ni = 0; ni < 4; ni++) acc[mi][ni][r] *= sc;
            }
    }
#pragma unroll
    for (int mi = 0; mi < 4; mi++)
#pragma unroll
        for (int ni = 0; ni < 4; ni++)
#pragma unroll
            for (int r = 0; r < 4; r++) {
                int row = m0 + wm + mi * 16 + quad * 4 + r;
                int col = n0 + wn + ni * 16 + l15;
                float v = acc[mi][ni][r];
                if (WRITE_F32)
                    ((float*)Cout)[(size_t)row * ldc + col] = v;
                else
                    ((bf16_t*)Cout)[(size_t)row * ldc + col] = (bf16_t)v;
            }
}

// ---- V (QKV cols 2048..3071) -> Vt[h][d][n], tokens in MFMA k-enum order ----------
// Within each 32-token tile, position kk holds token j(kk) = 16*((kk&7)>>2)
// + 4*(kk>>3) + (kk&3)  => PV A-fragment becomes ONE contiguous b128 LDS read.
__global__ __launch_bounds__(256) void transpose_v_kernel(const bf16_t* __restrict__ QKV,
                                                          bf16_t* __restrict__ Vt) {
    __shared__ bf16_t t[64][72];
    int n0 = blockIdx.x * 64;
    int h = blockIdx.y;
    int tx = threadIdx.x & 63, ty = threadIdx.x >> 6;
#pragma unroll
    for (int i = 0; i < 16; i++) {
        int nl = ty * 16 + i;
        t[nl][tx] = QKV[(size_t)(n0 + nl) * 3072 + 2048 + h * DH + tx];
    }
    __syncthreads();
    const int e = tx & 7, q = (tx >> 3) & 3;
    const int J = (tx & 32) + 16 * (e >> 2) + 4 * q + (e & 3);   // permuted token
#pragma unroll
    for (int i = 0; i < 16; i++) {
        int dl = ty * 16 + i;
        Vt[(size_t)(h * DH + dl) * N_TOK + n0 + tx] = t[J][dl];
    }
}

// ---------------- flash attention v9: S^T trick + k-enum V (no packing) ------------
// S^T = K.Q^T -> C-layout IS a B-fragment under k-enum j(q,e)=16*(e>>2)+4q+(e&3);
// V stored globally in that same k-enum order -> PV A-frag = 1 swizzled b128 read.
// Block = 4 waves x 16 q-rows (64-row group), K/V staged once (swizzled, dbuf).
__global__ __launch_bounds__(256) void attn_kernel(const bf16_t* __restrict__ QKV,
                                                   const bf16_t* __restrict__ Vt,
                                                   bf16_t* __restrict__ O) {
    __shared__ __align__(16) bf16_t Ks[2][2048];   // [buf][32 j x 64 d] chunk c@row r = src c^(r&7)
    __shared__ __align__(16) bf16_t Vs[2][2048];   // [buf][64 d x 32 kk] chunk c@row d = src c^((d>>1)&3)
    const int tid = threadIdx.x;
    const int wave = tid >> 6;
    const int lane = tid & 63;
    const int l15 = lane & 15;
    const int quad = lane >> 4;

    const int xcd = blockIdx.x & 7;
    const int t = blockIdx.x >> 3;          // 0..127
    const int h = xcd * 2 + (t & 1);        // 2 heads per XCD
    const int g = 63 - (t >> 1);            // 64-row i-group, heaviest first
    const int i0 = g * 64 + wave * 16;      // this wave's 16 rows
    const int jt_blk = 2 * g + 1;           // block's last j-tile
    const int jtw = 2 * g + (wave >> 1);    // this wave's diagonal tile

    const bf16_t* Qb = QKV + h * DH;
    const bf16_t* Kb = QKV + 1024 + h * DH;
    const bf16_t* Vb = Vt + (size_t)h * DH * N_TOK;

    // Q^T B-fragment: lane n=l15 -> row i0+l15, k=quad*8.. contiguous
    bf16x8 aq[2];
#pragma unroll
    for (int kd = 0; kd < 2; kd++)
        aq[kd] = *(const bf16x8*)(Qb + (size_t)(i0 + l15) * 3072 + kd * 32 + quad * 8);

    f32x4 od[4] = {};          // O^T[d=mt*16+quad*4+r][i=l15]
    float l_acc = 0.f;

    // staging: K chunk idx tid -> (row=tid>>3, c=tid&7), src chunk c^(row&7)
    const int krow = tid >> 3;
    const int kc = (tid & 7) ^ (krow & 7);
    const bf16_t* gK = Kb + (size_t)krow * 3072 + kc * 8;
    // V chunk idx tid -> (d=tid>>2, c=tid&3), src chunk c^((d>>1)&3)
    const int vd = tid >> 2;
    const int vc = (tid & 3) ^ ((vd >> 1) & 3);
    const bf16_t* gV = Vb + (size_t)vd * N_TOK + vc * 8;

    // preload tile 0 into buf 0
    async_copy16(gK, &Ks[0][tid * 8]);
    async_copy16(gV, &Vs[0][tid * 8]);

    const int ksw = l15 & 7;             // K-tile read swizzle
    const int vsw = (l15 >> 1) & 3;      // V-tile read swizzle (16B chunks)

    for (int jt = 0; jt <= jt_blk; jt++) {
        __syncthreads();                 // drains vmcnt: buf[jt&1] ready; prior reads done
        if (jt < jt_blk) {               // prefetch next tile into other buf
            const int b = (jt + 1) & 1;
            async_copy16(gK + (size_t)(jt + 1) * 32 * 3072, &Ks[b][tid * 8]);
            async_copy16(gV + (jt + 1) * 32, &Vs[b][tid * 8]);
        }
        if (jt > jtw) continue;          // wave-uniform; still hits barriers
        const bf16_t* KS = Ks[jt & 1];
        const bf16_t* VS = Vs[jt & 1];

        // ---- S^T = K.Q^T : A = K-frag (m=j), B = aq (n=i) ----
        bf16x8 ak[2][2];                 // [jh][kd]
#pragma unroll
        for (int jh = 0; jh < 2; jh++)
#pragma unroll
            for (int kd = 0; kd < 2; kd++)
                ak[jh][kd] = *(const bf16x8*)(&KS[(jh * 16 + l15) * 64 +
                                                  (((kd * 4 + quad) ^ ksw) * 8)]);
        f32x4 sj[2] = {};
#pragma unroll
        for (int kd = 0; kd < 2; kd++)
#pragma unroll
            for (int jh = 0; jh < 2; jh++)
                sj[jh] = __builtin_amdgcn_mfma_f32_16x16x32_bf16(ak[jh][kd], aq[kd], sj[jh], 0, 0, 0);

        // ---- softmax (fixed max), pack P^T B-fragment pk8[e]=p[e>>2][e&3] ----
        bf16x8 pk8;
        const int j_base = jt * 32 + quad * 4;
        const int i_row = i0 + l15;
        if (jt == jtw) {                 // diagonal tile: causal mask j > i
#pragma unroll
            for (int r = 0; r < 4; r++) {
                float p0 = (j_base + r > i_row) ? 0.f
                           : __builtin_amdgcn_exp2f(sj[0][r] * C1 - C2);
                float p1 = (j_base + 16 + r > i_row) ? 0.f
                           : __builtin_amdgcn_exp2f(sj[1][r] * C1 - C2);
                l_acc += p0 + p1;
                pk8[r] = (bf16_t)p0;
                pk8[4 + r] = (bf16_t)p1;
            }
        } else {
#pragma unroll
            for (int r = 0; r < 4; r++) {
                float p0 = __builtin_amdgcn_exp2f(sj[0][r] * C1 - C2);
                float p1 = __builtin_amdgcn_exp2f(sj[1][r] * C1 - C2);
                l_acc += p0 + p1;
                pk8[r] = (bf16_t)p0;
                pk8[4 + r] = (bf16_t)p1;
            }
        }

        // ---- O^T += V^T.P^T : A-frag = ONE b128 read (k-enum global layout) ----
#pragma unroll
        for (int mt = 0; mt < 4; mt++) {
            bf16x8 vf = *(const bf16x8*)(&VS[(mt * 16 + l15) * 32 + ((quad ^ vsw) * 8)]);
            od[mt] = __builtin_amdgcn_mfma_f32_16x16x32_bf16(vf, pk8, od[mt], 0, 0, 0);
        }
    }

    // ---- normalize: row sum l for i=l15 lives split across quads ----
    float l = l_acc;
    l += __shfl_xor(l, 16);
    l += __shfl_xor(l, 32);
    float inv = 1.0f / l;

#pragma unroll
    for (int mt = 0; mt < 4; mt++) {
        bf16x4 o;
#pragma unroll
        for (int r = 0; r < 4; r++) o[r] = (bf16_t)(od[mt][r] * inv);
        *(bf16x4*)(&O[(size_t)(i0 + l15) * D_MODEL + h * DH + mt * 16 + quad * 4]) = o;
    }
}

extern "C" void kernel_launch(void* const* d_in, const int* in_sizes, int n_in,
                              void* d_out, int out_size, void* d_ws, size_t ws_size,
                              hipStream_t stream) {
    const float* x  = (const float*)d_in[0];
    const float* Wq = (const float*)d_in[1];
    const float* Wk = (const float*)d_in[2];
    const float* Wv = (const float*)d_in[3];
    const float* Wo = (const float*)d_in[4];
    float* out = (float*)d_out;
    char* ws = (char*)d_ws;
    const size_t MB = 1024 * 1024;
    bf16_t* xb   = (bf16_t*)(ws);             // 8 MB
    bf16_t* Wt3  = (bf16_t*)(ws + 8 * MB);    // 6 MB  [3072][1024] q|k|v
    bf16_t* Wot  = (bf16_t*)(ws + 14 * MB);   // 2 MB
    bf16_t* QKV  = (bf16_t*)(ws + 16 * MB);   // 24 MB [4096][3072]
    bf16_t* Vt   = (bf16_t*)(ws + 40 * MB);   // 8 MB  [16][64][4096] (k-enum order)
    bf16_t* Ob   = (bf16_t*)(ws + 48 * MB);   // 8 MB  -> ends at 56 MB

    cast_x_kernel<<<4096, 256, 0, stream>>>(x, xb);
    dim3 gw(16, 16, 4);
    transpose_w_kernel<<<gw, 256, 0, stream>>>(Wq, Wk, Wv, Wo,
                                               Wt3, Wt3 + 1024 * 1024, Wt3 + 2 * 1024 * 1024, Wot);
    dim3 gqkv(3072 / 128, N_TOK / 128);
    gemm_tile<0, 1><<<gqkv, 256, 0, stream>>>(xb, Wt3, QKV, 3072);
    dim3 gv(N_TOK / 64, HEADS);
    transpose_v_kernel<<<gv, 256, 0, stream>>>(QKV, Vt);
    attn_kernel<<<1024, 256, 0, stream>>>(QKV, Vt, Ob);
    dim3 go(D_MODEL / 128, N_TOK / 128);
    gemm_tile<1, 0><<<go, 256, 0, stream>>>(Ob, Wot, out, D_MODEL);
}

// Round 10
// 208.832 us; speedup vs baseline: 1.3497x; 1.1888x over previous
//
#include <hip/hip_runtime.h>
#include <stdint.h>
#include <math.h>

typedef __bf16 bf16_t;
typedef __attribute__((ext_vector_type(8))) __bf16 bf16x8;
typedef __attribute__((ext_vector_type(4))) __bf16 bf16x4;
typedef __attribute__((ext_vector_type(4))) float f32x4;

#define N_TOK 4096
#define D_MODEL 1024
#define HEADS 16
#define DH 64
// p = exp(8*dot - 8.125) = exp2(dot*C1 - C2); constant shift cancels in softmax.
#define C1 11.541560327111707f   // 8 * log2(e)
#define C2 11.721897207207671f   // 8.125 * log2(e)

// async global->LDS 16B copy (dest = wave-uniform base + lane*16)
__device__ __forceinline__ void async_copy16(const void* g, void* l) {
    __builtin_amdgcn_global_load_lds(
        (const __attribute__((address_space(1))) unsigned int*)g,
        (__attribute__((address_space(3))) unsigned int*)l, 16, 0, 0);
}

// ---------------- cast x -> bf16 ----------------
__global__ __launch_bounds__(256) void cast_x_kernel(const float* __restrict__ x,
                                                     bf16_t* __restrict__ xb) {
    int i = (blockIdx.x * 256 + threadIdx.x) * 4;
    float4 v = *(const float4*)(x + i);
    bf16x4 o;
    o[0] = (bf16_t)v.x; o[1] = (bf16_t)v.y; o[2] = (bf16_t)v.z; o[3] = (bf16_t)v.w;
    *(bf16x4*)(xb + i) = o;
}

// ------- transpose + cast W[k][n] -> Wt[n][k] bf16 (q,k,v into one 3072-row buf) ----
__global__ __launch_bounds__(256) void transpose_w_kernel(
    const float* __restrict__ W0, const float* __restrict__ W1,
    const float* __restrict__ W2, const float* __restrict__ W3,
    bf16_t* __restrict__ T0, bf16_t* __restrict__ T1,
    bf16_t* __restrict__ T2, bf16_t* __restrict__ T3) {
    __shared__ bf16_t t[64][72];
    const float* W; bf16_t* T;
    switch (blockIdx.z) {
        case 0: W = W0; T = T0; break;
        case 1: W = W1; T = T1; break;
        case 2: W = W2; T = T2; break;
        default: W = W3; T = T3; break;
    }
    int k0 = blockIdx.x * 64, n0 = blockIdx.y * 64;
    int tx = threadIdx.x & 63, ty = threadIdx.x >> 6;
#pragma unroll
    for (int i = 0; i < 16; i++) {
        int kl = ty * 16 + i;
        t[kl][tx] = (bf16_t)W[(size_t)(k0 + kl) * D_MODEL + n0 + tx];
    }
    __syncthreads();
#pragma unroll
    for (int i = 0; i < 16; i++) {
        int nl = ty * 16 + i;
        T[(size_t)(n0 + nl) * D_MODEL + k0 + tx] = t[tx][nl];
    }
}

// ------- 128x128 MFMA GEMM, m97-exact staging (sequential chunks, BK=32) -----------
// C[M][ldc] tile = A[M][1024] * Bt[N][1024]^T ; optional fused L2-norm per 64-col head
template <int WRITE_F32, int NORM>
__global__ __launch_bounds__(256) void gemm_tile(const bf16_t* __restrict__ A,
                                                 const bf16_t* __restrict__ Bt,
                                                 void* __restrict__ Cout, int ldc) {
    constexpr int K = D_MODEL;
    __shared__ __align__(16) bf16_t As[128 * 32];
    __shared__ __align__(16) bf16_t Bs[128 * 32];
    const int tid = threadIdx.x;
    const int m0 = blockIdx.y * 128;
    const int n0 = blockIdx.x * 128;
    const int wave = tid >> 6;
    const int lane = tid & 63;
    const int l15 = lane & 15;
    const int quad = lane >> 4;
    const int wm = (wave >> 1) * 64;
    const int wn = (wave & 1) * 64;
    f32x4 acc[4][4] = {};

    // staging: thread t handles chunks t and t+256; chunk c: row=c>>2, off=(c&3)*8
    const int srow = tid >> 2;
    const int soff = (tid & 3) * 8;
    const bf16_t* gA = A + (size_t)(m0 + srow) * K + soff;
    const bf16_t* gB = Bt + (size_t)(n0 + srow) * K + soff;
    bf16_t* lA = &As[tid * 8];
    bf16_t* lB = &Bs[tid * 8];
    constexpr int HGAP = 64 * K;

    for (int kt = 0; kt < K; kt += 32) {
        __syncthreads();
        async_copy16(gA + kt, lA);
        async_copy16(gA + HGAP + kt, lA + 2048);
        async_copy16(gB + kt, lB);
        async_copy16(gB + HGAP + kt, lB + 2048);
        __syncthreads();
        bf16x8 af[4], bfr[4];
#pragma unroll
        for (int mi = 0; mi < 4; mi++)
            af[mi] = *(const bf16x8*)(&As[(wm + mi * 16 + l15) * 32 + quad * 8]);
#pragma unroll
        for (int ni = 0; ni < 4; ni++)
            bfr[ni] = *(const bf16x8*)(&Bs[(wn + ni * 16 + l15) * 32 + quad * 8]);
#pragma unroll
        for (int mi = 0; mi < 4; mi++)
#pragma unroll
            for (int ni = 0; ni < 4; ni++)
                acc[mi][ni] = __builtin_amdgcn_mfma_f32_16x16x32_bf16(
                    af[mi], bfr[ni], acc[mi][ni], 0, 0, 0);
    }

    if (NORM && n0 < 2048) {   // wave's 64-col span == one head: fused F.normalize
#pragma unroll
        for (int mi = 0; mi < 4; mi++)
#pragma unroll
            for (int r = 0; r < 4; r++) {
                float s = 0.f;
#pragma unroll
                for (int ni = 0; ni < 4; ni++) {
                    float v = acc[mi][ni][r];
                    s += v * v;
                }
                s += __shfl_xor(s, 1);
                s += __shfl_xor(s, 2);
                s += __shfl_xor(s, 4);
                s += __shfl_xor(s, 8);
                float sc = 1.0f / fmaxf(sqrtf(s), 1e-12f);
#pragma unroll
                for (int ni = 0; ni < 4; ni++) acc[mi][ni][r] *= sc;
            }
    }
#pragma unroll
    for (int mi = 0; mi < 4; mi++)
#pragma unroll
        for (int ni = 0; ni < 4; ni++)
#pragma unroll
            for (int r = 0; r < 4; r++) {
                int row = m0 + wm + mi * 16 + quad * 4 + r;
                int col = n0 + wn + ni * 16 + l15;
                float v = acc[mi][ni][r];
                if (WRITE_F32)
                    ((float*)Cout)[(size_t)row * ldc + col] = v;
                else
                    ((bf16_t*)Cout)[(size_t)row * ldc + col] = (bf16_t)v;
            }
}

// ---- V (QKV cols 2048..3071) -> Vt[h][d][n], tokens in MFMA k-enum order ----------
// Within each 32-token tile, position kk holds token j(kk) = 16*((kk&7)>>2)
// + 4*(kk>>3) + (kk&3)  => PV A-fragment becomes ONE contiguous b128 LDS read.
__global__ __launch_bounds__(256) void transpose_v_kernel(const bf16_t* __restrict__ QKV,
                                                          bf16_t* __restrict__ Vt) {
    __shared__ bf16_t t[64][72];
    int n0 = blockIdx.x * 64;
    int h = blockIdx.y;
    int tx = threadIdx.x & 63, ty = threadIdx.x >> 6;
#pragma unroll
    for (int i = 0; i < 16; i++) {
        int nl = ty * 16 + i;
        t[nl][tx] = QKV[(size_t)(n0 + nl) * 3072 + 2048 + h * DH + tx];
    }
    __syncthreads();
    const int e = tx & 7, q = (tx >> 3) & 3;
    const int J = (tx & 32) + 16 * (e >> 2) + 4 * q + (e & 3);   // permuted token
#pragma unroll
    for (int i = 0; i < 16; i++) {
        int dl = ty * 16 + i;
        Vt[(size_t)(h * DH + dl) * N_TOK + n0 + tx] = t[J][dl];
    }
}

// ---------------- flash attention v10: 64-wide j-tiles, S^T trick -------------------
// Block = 4 waves x 16 q-rows (64-row group g). Tile = 64 j x 64 d (16KB K+V),
// dbuf, ONE barrier per 64 j (half of v9). 16 MFMA + 16 exp2 per interior tile,
// 4 independent jh-streams for ILP. Diagonal tile (jt==g): wave w does jh <= w.
__global__ __launch_bounds__(256) void attn_kernel(const bf16_t* __restrict__ QKV,
                                                   const bf16_t* __restrict__ Vt,
                                                   bf16_t* __restrict__ O) {
    __shared__ __align__(16) bf16_t Ks[2][4096];      // [buf][64 j x 64 d] chunk c@row = src c^(row&7)
    __shared__ __align__(16) bf16_t Vs[2][2][2048];   // [buf][half][64 d x 32 kk] chunk c@row d = src c^((d>>1)&3)
    const int tid = threadIdx.x;
    const int wave = tid >> 6;
    const int lane = tid & 63;
    const int l15 = lane & 15;
    const int quad = lane >> 4;

    const int xcd = blockIdx.x & 7;
    const int t = blockIdx.x >> 3;          // 0..127
    const int h = xcd * 2 + (t & 1);        // 2 heads per XCD
    const int g = 63 - (t >> 1);            // 64-row i-group, heaviest first
    const int i0 = g * 64 + wave * 16;      // this wave's 16 rows

    const bf16_t* Qb = QKV + h * DH;
    const bf16_t* Kb = QKV + 1024 + h * DH;
    const bf16_t* Vb = Vt + (size_t)h * DH * N_TOK;

    // Q^T B-fragment: lane n=l15 -> row i0+l15, k=quad*8.. contiguous
    bf16x8 aq[2];
#pragma unroll
    for (int kd = 0; kd < 2; kd++)
        aq[kd] = *(const bf16x8*)(Qb + (size_t)(i0 + l15) * 3072 + kd * 32 + quad * 8);

    f32x4 od[4] = {};          // O^T[d=mt*16+quad*4+r][i=l15]
    float l_acc = 0.f;

    // staging: K chunk idx L=tid+256*i -> (row=(tid>>3)+32*i, c=tid&7), src c^(row&7)
    const int krow = tid >> 3;
    const int kc = (tid & 7) ^ (krow & 7);
    const bf16_t* gK = Kb + (size_t)krow * 3072 + kc * 8;
    // V chunk idx tid -> (d=tid>>2, c=tid&3), src chunk c^((d>>1)&3); two 32-kk halves
    const int vd = tid >> 2;
    const int vc = (tid & 3) ^ ((vd >> 1) & 3);
    const bf16_t* gV = Vb + (size_t)vd * N_TOK + vc * 8;

    // preload tile 0 into buf 0
    async_copy16(gK, &Ks[0][tid * 8]);
    async_copy16(gK + (size_t)32 * 3072, &Ks[0][tid * 8 + 2048]);
    async_copy16(gV, &Vs[0][0][tid * 8]);
    async_copy16(gV + 32, &Vs[0][1][tid * 8]);

    const int ksw = l15 & 7;             // K-tile read swizzle
    const int vsw = (l15 >> 1) & 3;      // V-tile read swizzle (16B chunks)

    for (int jt = 0; jt <= g; jt++) {
        __syncthreads();                 // drains vmcnt: buf[jt&1] ready; prior reads done
        if (jt < g) {                    // prefetch next tile into other buf
            const int b = (jt + 1) & 1;
            const bf16_t* kn = gK + (size_t)(jt + 1) * 64 * 3072;
            async_copy16(kn, &Ks[b][tid * 8]);
            async_copy16(kn + (size_t)32 * 3072, &Ks[b][tid * 8 + 2048]);
            async_copy16(gV + (jt + 1) * 64, &Vs[b][0][tid * 8]);
            async_copy16(gV + (jt + 1) * 64 + 32, &Vs[b][1][tid * 8]);
        }
        const bf16_t* KS = Ks[jt & 1];
        const bool diag = (jt == g);
        const int jh_max = diag ? wave : 3;

        // ---- S^T = K.Q^T over 4 jh sub-tiles (independent chains) ----
        bf16x8 ak[4][2];
#pragma unroll
        for (int jh = 0; jh < 4; jh++) {
            if (jh > jh_max) continue;
#pragma unroll
            for (int kd = 0; kd < 2; kd++)
                ak[jh][kd] = *(const bf16x8*)(&KS[(jh * 16 + l15) * 64 +
                                                  (((kd * 4 + quad) ^ ksw) * 8)]);
        }
        f32x4 sj[4] = {};
#pragma unroll
        for (int kd = 0; kd < 2; kd++)
#pragma unroll
            for (int jh = 0; jh < 4; jh++) {
                if (jh > jh_max) continue;
                sj[jh] = __builtin_amdgcn_mfma_f32_16x16x32_bf16(ak[jh][kd], aq[kd], sj[jh], 0, 0, 0);
            }

        // ---- softmax (fixed max); mask only the jh==wave sub-tile on the diagonal ----
        float p[4][4] = {};
#pragma unroll
        for (int jh = 0; jh < 4; jh++) {
            if (jh > jh_max) continue;
            if (diag && jh == wave) {
#pragma unroll
                for (int r = 0; r < 4; r++) {
                    float v = (quad * 4 + r > l15) ? 0.f
                              : __builtin_amdgcn_exp2f(sj[jh][r] * C1 - C2);
                    p[jh][r] = v;
                    l_acc += v;
                }
            } else {
#pragma unroll
                for (int r = 0; r < 4; r++) {
                    float v = __builtin_amdgcn_exp2f(sj[jh][r] * C1 - C2);
                    p[jh][r] = v;
                    l_acc += v;
                }
            }
        }
        // pack P^T B-fragments: half H covers jh = 2H, 2H+1 (k-enum j(q,e))
        bf16x8 pk8[2];
#pragma unroll
        for (int H = 0; H < 2; H++)
#pragma unroll
            for (int r = 0; r < 4; r++) {
                pk8[H][r] = (bf16_t)p[2 * H][r];
                pk8[H][4 + r] = (bf16_t)p[2 * H + 1][r];
            }

        // ---- O^T += V^T.P^T : one b128 A-frag per (mt, half) ----
        const bf16_t* VS0 = Vs[jt & 1][0];
#pragma unroll
        for (int mt = 0; mt < 4; mt++) {
            bf16x8 vf = *(const bf16x8*)(&VS0[(mt * 16 + l15) * 32 + ((quad ^ vsw) * 8)]);
            od[mt] = __builtin_amdgcn_mfma_f32_16x16x32_bf16(vf, pk8[0], od[mt], 0, 0, 0);
        }
        if (jh_max >= 2) {
            const bf16_t* VS1 = Vs[jt & 1][1];
#pragma unroll
            for (int mt = 0; mt < 4; mt++) {
                bf16x8 vf = *(const bf16x8*)(&VS1[(mt * 16 + l15) * 32 + ((quad ^ vsw) * 8)]);
                od[mt] = __builtin_amdgcn_mfma_f32_16x16x32_bf16(vf, pk8[1], od[mt], 0, 0, 0);
            }
        }
    }

    // ---- normalize: row sum l for i=l15 lives split across quads ----
    float l = l_acc;
    l += __shfl_xor(l, 16);
    l += __shfl_xor(l, 32);
    float inv = 1.0f / l;

#pragma unroll
    for (int mt = 0; mt < 4; mt++) {
        bf16x4 o;
#pragma unroll
        for (int r = 0; r < 4; r++) o[r] = (bf16_t)(od[mt][r] * inv);
        *(bf16x4*)(&O[(size_t)(i0 + l15) * D_MODEL + h * DH + mt * 16 + quad * 4]) = o;
    }
}

extern "C" void kernel_launch(void* const* d_in, const int* in_sizes, int n_in,
                              void* d_out, int out_size, void* d_ws, size_t ws_size,
                              hipStream_t stream) {
    const float* x  = (const float*)d_in[0];
    const float* Wq = (const float*)d_in[1];
    const float* Wk = (const float*)d_in[2];
    const float* Wv = (const float*)d_in[3];
    const float* Wo = (const float*)d_in[4];
    float* out = (float*)d_out;
    char* ws = (char*)d_ws;
    const size_t MB = 1024 * 1024;
    bf16_t* xb   = (bf16_t*)(ws);             // 8 MB
    bf16_t* Wt3  = (bf16_t*)(ws + 8 * MB);    // 6 MB  [3072][1024] q|k|v
    bf16_t* Wot  = (bf16_t*)(ws + 14 * MB);   // 2 MB
    bf16_t* QKV  = (bf16_t*)(ws + 16 * MB);   // 24 MB [4096][3072]
    bf16_t* Vt   = (bf16_t*)(ws + 40 * MB);   // 8 MB  [16][64][4096] (k-enum order)
    bf16_t* Ob   = (bf16_t*)(ws + 48 * MB);   // 8 MB  -> ends at 56 MB

    cast_x_kernel<<<4096, 256, 0, stream>>>(x, xb);
    dim3 gw(16, 16, 4);
    transpose_w_kernel<<<gw, 256, 0, stream>>>(Wq, Wk, Wv, Wo,
                                               Wt3, Wt3 + 1024 * 1024, Wt3 + 2 * 1024 * 1024, Wot);
    dim3 gqkv(3072 / 128, N_TOK / 128);
    gemm_tile<0, 1><<<gqkv, 256, 0, stream>>>(xb, Wt3, QKV, 3072);
    dim3 gv(N_TOK / 64, HEADS);
    transpose_v_kernel<<<gv, 256, 0, stream>>>(QKV, Vt);
    attn_kernel<<<1024, 256, 0, stream>>>(QKV, Vt, Ob);
    dim3 go(D_MODEL / 128, N_TOK / 128);
    gemm_tile<1, 0><<<go, 256, 0, stream>>>(Ob, Wot, out, D_MODEL);
}